// Round 5
// baseline (3714.523 us; speedup 1.0000x reference)
//
#include <hip/hip_runtime.h>

// MDN-RNN persistent kernel for MI355X (gfx950).  R5: poll-on-data + reg-resident B.
// B=128, T=1000, D_IN=35, H=512, OUT=480.
// 8 batch-groups (16 batches) x 32 h-slice WGs = 256 WGs, 1/CU.
// R4 lesson: relaxed agent-scope (cache-bypass) atomics avoid wbl2/inv storms.
// R5: (a) h exchange = u64 {epoch32 | h1 | h0} words; consumers poll their own
// words until epoch==t+1 and unpack directly -> 1 visible RT instead of 3
// (store-drain + flag-poll + h-load). Safety: distance-2 double-buffer argument
// proves no word is overwritten before all consumers of the previous epoch read
// it (producer at t passed poll of h_{t-1} => every peer finished step t-2).
// (b) B-fragments (Wr/Wk/Wd slices) are step-invariant -> hoisted into 18
// bf16x8 registers per thread; gate waves do 18 ds_read_b128/step (A only).

#define NGRP   8
#define NSLICE 32
#define GB     16
#define HH     512
#define TT     1000
#define DIN    35
#define OUTC   480
#define ODC    15

typedef __bf16 bf16x8 __attribute__((ext_vector_type(8)));
typedef float  f32x4  __attribute__((ext_vector_type(4)));
typedef unsigned short u16;
typedef unsigned int   u32;
typedef unsigned long long u64;

__device__ __forceinline__ u16 f2bf(float x) {
    unsigned int u = __float_as_uint(x);
    u += 0x7FFFu + ((u >> 16) & 1u);
    return (u16)(u >> 16);
}
__device__ __forceinline__ float sigf(float x) { return 1.0f / (1.0f + __expf(-x)); }
__device__ __forceinline__ float tanh_fast(float x) {
    float ax = fabsf(x);
    float e = __expf(-2.0f * ax);
    return copysignf((1.0f - e) / (1.0f + e), x);
}

__global__ void __launch_bounds__(512, 1)
mdn_kernel(const float* __restrict__ inp, const float* __restrict__ Wk,
           const float* __restrict__ Wr,  const float* __restrict__ bg,
           const float* __restrict__ Wd,  const float* __restrict__ bd,
           float* __restrict__ out, u64* __restrict__ hx)
{
    __shared__ __attribute__((aligned(16))) u16  wr_s[64 * HH];   // dead after preamble
    __shared__ __attribute__((aligned(16))) u16  wk_s[64 * 64];   // dead after preamble
    __shared__ __attribute__((aligned(16))) u16  wd_s[16 * HH];   // dead after preamble
    __shared__ __attribute__((aligned(16))) u16  h_s [GB * HH];
    __shared__ __attribute__((aligned(16))) u16  in_s[GB * 64];
    __shared__ __attribute__((aligned(16))) float gbuf[4 * 16 * 16]; // [q][batch][col]
    __shared__ __attribute__((aligned(16))) float pbuf[4 * 16 * 16]; // [kw][batch][col]

    const int tid  = threadIdx.x;
    const int lane = tid & 63;
    const int wave = tid >> 6;
    const int g    = blockIdx.x & 7;    // batch group
    const int s    = blockIdx.x >> 3;   // h-slice 0..31
    const int m16  = lane & 15;
    const int kq   = lane >> 4;

    // ---------------- region A: weight staging + LDS zero-init ----------------
    {
        int n = tid & 63;
        int q = n >> 4, jj = n & 15;
        int col = q * HH + s * 16 + jj;
        for (int k = tid >> 6; k < HH; k += 8)
            wr_s[n * HH + (k ^ ((n & 7) << 3))] = f2bf(Wr[(size_t)k * 2048 + col]);
        for (int k = tid >> 6; k < 64; k += 8)
            wk_s[n * 64 + (k ^ ((n & 7) << 3))] = f2bf(k < DIN ? Wk[(size_t)k * 2048 + col] : 0.0f);
    }
    {
        int n = tid & 15;
        for (int k = tid >> 4; k < HH; k += 32)
            wd_s[n * HH + (k ^ ((n & 7) << 3))] =
                f2bf(n < ODC ? Wd[(size_t)k * OUTC + s * ODC + n] : 0.0f);
    }
    for (int i = tid; i < GB * 64; i += 512) in_s[i] = 0;
    for (int i = tid; i < GB * HH / 8; i += 512) ((uint4*)h_s)[i] = uint4{0,0,0,0}; // h_{-1}=0

    __syncthreads();

    // ---------------- region B: B-frags to registers, state, x_0 ----------------
    bf16x8 bfr[18];
    if (wave < 4) {
        int n = wave * 16 + m16;
        #pragma unroll
        for (int ks = 0; ks < 16; ++ks) {
            int k0 = 32 * ks + 8 * kq;
            bfr[ks] = *(const bf16x8*)(&wr_s[n * HH + (k0 ^ ((n & 7) << 3))]);
        }
        #pragma unroll
        for (int i = 0; i < 2; ++i) {
            int k0 = 32 * i + 8 * kq;
            bfr[16 + i] = *(const bf16x8*)(&wk_s[n * 64 + (k0 ^ ((n & 7) << 3))]);
        }
    } else {
        int w4 = wave - 4;
        #pragma unroll
        for (int kk = 0; kk < 4; ++kk) {
            int k0 = w4 * 128 + 32 * kk + 8 * kq;
            bfr[kk] = *(const bf16x8*)(&wd_s[m16 * HH + (k0 ^ ((m16 & 7) << 3))]);
        }
    }

    float c_reg = 0.0f;
    float bi = 0.f, bff = 0.f, bgg = 0.f, boo = 0.f, bdv = 0.f;
    int br = 0, jj = 0, oo = 0;
    if (tid < 256) {
        br = tid >> 4; jj = tid & 15;
        int scol = s * 16 + jj;
        bi  = bg[0 * HH + scol];
        bff = bg[1 * HH + scol];
        bgg = bg[2 * HH + scol];
        boo = bg[3 * HH + scol];
        // stage x_0
        const float* ip = inp + ((size_t)(g * GB + br) * TT + 0) * DIN;
        #pragma unroll
        for (int i = 0; i < 3; ++i) {
            int d = jj + 16 * i;
            if (d < DIN) in_s[br * 64 + (d ^ ((br & 7) << 3))] = f2bf(ip[d]);
        }
    } else {
        br = (tid - 256) >> 4; oo = (tid - 256) & 15;
        if (oo < ODC) bdv = bd[s * ODC + oo];
    }
    __syncthreads();

    // poll geometry: thread owns 8 u64 words of h (16 values)
    const int pb = tid >> 5;      // batch row 0..15
    const int pk = tid & 31;      // covers k = pk*8 + i*256, i=0,1

    for (int t = 0; t <= TT; ++t) {
        // invariant: h_s = h_{t-1}, in_s = x_t
        // ---- MFMA phase (B from registers, A from LDS) ----
        if (wave < 4) {
            if (t < TT) {
                f32x4 acc0 = {0.f,0.f,0.f,0.f}, acc1 = {0.f,0.f,0.f,0.f};
                {   // xz contribution (K padded 35->64)
                    int k0 = 8 * kq;
                    bf16x8 a = *(const bf16x8*)(&in_s[m16 * 64 + (k0 ^ ((m16 & 7) << 3))]);
                    acc0 = __builtin_amdgcn_mfma_f32_16x16x32_bf16(a, bfr[16], acc0, 0, 0, 0);
                    int k1 = 32 + 8 * kq;
                    bf16x8 a2 = *(const bf16x8*)(&in_s[m16 * 64 + (k1 ^ ((m16 & 7) << 3))]);
                    acc1 = __builtin_amdgcn_mfma_f32_16x16x32_bf16(a2, bfr[17], acc1, 0, 0, 0);
                }
                #pragma unroll
                for (int ks = 0; ks < 16; ks += 2) {   // h @ Wr, 2-way ILP
                    int k0 = 32 * ks + 8 * kq;
                    bf16x8 a = *(const bf16x8*)(&h_s[m16 * HH + (k0 ^ ((m16 & 7) << 3))]);
                    acc0 = __builtin_amdgcn_mfma_f32_16x16x32_bf16(a, bfr[ks], acc0, 0, 0, 0);
                    int k1 = 32 * (ks + 1) + 8 * kq;
                    bf16x8 a2 = *(const bf16x8*)(&h_s[m16 * HH + (k1 ^ ((m16 & 7) << 3))]);
                    acc1 = __builtin_amdgcn_mfma_f32_16x16x32_bf16(a2, bfr[ks + 1], acc1, 0, 0, 0);
                }
                #pragma unroll
                for (int j = 0; j < 4; ++j)
                    gbuf[wave * 256 + (kq * 4 + j) * 16 + m16] = acc0[j] + acc1[j];
            }
        } else {
            if (t > 0) {    // out row t-1, k-split across waves 4..7
                int w4 = wave - 4;
                f32x4 acc0 = {0.f,0.f,0.f,0.f}, acc1 = {0.f,0.f,0.f,0.f};
                #pragma unroll
                for (int kk = 0; kk < 4; kk += 2) {
                    int k0 = w4 * 128 + 32 * kk + 8 * kq;
                    bf16x8 a = *(const bf16x8*)(&h_s[m16 * HH + (k0 ^ ((m16 & 7) << 3))]);
                    acc0 = __builtin_amdgcn_mfma_f32_16x16x32_bf16(a, bfr[kk], acc0, 0, 0, 0);
                    int k1 = w4 * 128 + 32 * (kk + 1) + 8 * kq;
                    bf16x8 a2 = *(const bf16x8*)(&h_s[m16 * HH + (k1 ^ ((m16 & 7) << 3))]);
                    acc1 = __builtin_amdgcn_mfma_f32_16x16x32_bf16(a2, bfr[kk + 1], acc1, 0, 0, 0);
                }
                #pragma unroll
                for (int j = 0; j < 4; ++j)
                    pbuf[w4 * 256 + (kq * 4 + j) * 16 + m16] = acc0[j] + acc1[j];
            }
        }
        __syncthreads();                                   // #1

        // ---- scalar phase ----
        if (tid < 256) {
            if (t < TT) {
                float iv = gbuf[0 * 256 + br * 16 + jj] + bi;
                float fv = gbuf[1 * 256 + br * 16 + jj] + bff;
                float gv = gbuf[2 * 256 + br * 16 + jj] + bgg;
                float ov = gbuf[3 * 256 + br * 16 + jj] + boo;
                c_reg = sigf(fv) * c_reg + sigf(iv) * tanh_fast(gv);
                float h = sigf(ov) * tanh_fast(c_reg);
                // publish {epoch | h1 | h0} as one relaxed agent u64 (cache-bypass)
                u32 hb = (u32)f2bf(h);
                u32 other = (u32)__shfl_xor((int)hb, 1);
                if ((jj & 1) == 0) {
                    u64 val = ((u64)(u32)(t + 1) << 32) | (u64)((other << 16) | hb);
                    u64* dst = hx + ((size_t)(g * 2 + (t & 1))) * 4096
                                  + br * 256 + s * 8 + (jj >> 1);
                    __hip_atomic_store(dst, val, __ATOMIC_RELAXED, __HIP_MEMORY_SCOPE_AGENT);
                }
            }
        } else {
            if (t > 0) {    // reduce out partials + store f32
                float v = pbuf[0 * 256 + br * 16 + oo] + pbuf[1 * 256 + br * 16 + oo]
                        + pbuf[2 * 256 + br * 16 + oo] + pbuf[3 * 256 + br * 16 + oo] + bdv;
                if (oo < ODC)
                    out[((size_t)(g * GB + br) * TT + (t - 1)) * OUTC + s * ODC + oo] = v;
            }
            // prefetch x_{t+1} (only writes d<35 slots; pad stays 0 -> no race)
            if (t + 1 < TT) {
                const float* ip = inp + ((size_t)(g * GB + br) * TT + (t + 1)) * DIN;
                #pragma unroll
                for (int i = 0; i < 3; ++i) {
                    int d = oo + 16 * i;
                    if (d < DIN) in_s[br * 64 + (d ^ ((br & 7) << 3))] = f2bf(ip[d]);
                }
            }
        }

        // ---- poll-on-data: wait for h_t words (epoch t+1), unpack into h_s ----
        if (t < TT) {
            const u64* base = hx + ((size_t)(g * 2 + (t & 1))) * 4096;
            const u32 target = (u32)(t + 1);
            u64 vv[8];
            bool fr[8] = {false,false,false,false,false,false,false,false};
            int spins = 0;
            while (true) {
                bool all = true;
                #pragma unroll
                for (int j = 0; j < 8; ++j) {
                    if (!fr[j]) {
                        int idx = pb * 256 + (j >> 2) * 128 + pk * 4 + (j & 3);
                        vv[j] = __hip_atomic_load(base + idx, __ATOMIC_RELAXED,
                                                  __HIP_MEMORY_SCOPE_AGENT);
                        fr[j] = ((u32)(vv[j] >> 32) == target);
                        if (!fr[j]) all = false;
                    }
                }
                if (all) break;
                if (++spins > (1 << 20)) break;            // bounded bail-out: no hangs
                __builtin_amdgcn_s_sleep(1);
            }
            #pragma unroll
            for (int i = 0; i < 2; ++i) {
                int k  = pk * 8 + i * 256;
                int sk = k ^ ((pb & 7) << 3);              // XOR moves 8-blocks whole
                u64 wlo = (vv[i*4+0] & 0xFFFFFFFFull) | (vv[i*4+1] << 32);
                u64 whi = (vv[i*4+2] & 0xFFFFFFFFull) | (vv[i*4+3] << 32);
                *(u64*)(&h_s[pb * HH + sk])     = wlo;
                *(u64*)(&h_s[pb * HH + sk + 4]) = whi;
            }
            __syncthreads();                               // #2
        }
    }
}

extern "C" void kernel_launch(void* const* d_in, const int* in_sizes, int n_in,
                              void* d_out, int out_size, void* d_ws, size_t ws_size,
                              hipStream_t stream) {
    const float* inp = (const float*)d_in[0];
    const float* Wk  = (const float*)d_in[1];
    const float* Wr  = (const float*)d_in[2];
    const float* bg  = (const float*)d_in[3];
    const float* Wd  = (const float*)d_in[4];
    const float* bd  = (const float*)d_in[5];
    float* out = (float*)d_out;

    // ws: h exchange words, 8 groups x 2 parities x 4096 u64 {epoch32|h1|h0} = 512 KB.
    // Must be zeroed every launch: stale epochs from a previous replay would
    // satisfy polls with old data (harness does not re-poison ws between replays).
    u64* hx = (u64*)d_ws;
    size_t zbytes = (size_t)NGRP * 2 * 4096 * sizeof(u64);
    hipMemsetAsync(d_ws, 0, zbytes, stream);

    hipLaunchKernelGGL(mdn_kernel, dim3(NGRP * NSLICE), dim3(512), 0, stream,
                       inp, Wk, Wr, bg, Wd, bd, out, hx);
}

// Round 6
// 3483.042 us; speedup vs baseline: 1.0665x; 1.0665x over previous
//
#include <hip/hip_runtime.h>

// MDN-RNN persistent kernel for MI355X (gfx950).  R6: sentinel 3-buffer exchange.
// B=128, T=1000, D_IN=35, H=512, OUT=480.
// 8 batch-groups (16 batches) x 32 h-slice WGs = 256 WGs, 1/CU.
// Exchange protocol (no flags, no drains on the critical path):
//   h(t) -> buf[t%3] as u64 words of 4 bf16; h in (-1,1) so 0xFFFF (NaN) never
//   occurs -> ~0ull is a safe "empty" sentinel. Consumers poll exactly their own
//   2048 words until != sentinel (data IS the flag; zero read amplification).
//   Producer at step t resets its own words of buf[(t+1)%3] (holds h(t-2), dead:
//   step-t poll of h(t-1) passing proves all slices read h(t-2)); one vmcnt(0)
//   between resets and h(t) stores (hidden under the MFMA phase) gives the
//   visibility chain: consumer saw h(t) => reset committed => no stale reads.
// R5 lesson: epoch-in-word doubled write+poll traffic and saturated the MALL
// atomic path; R4 lesson: relaxed agent atomics only (no wbl2/inv storms).

#define NGRP   8
#define NSLICE 32
#define GB     16
#define HH     512
#define TT     1000
#define DIN    35
#define OUTC   480
#define ODC    15
#define HWORDS 2048      // u64 words per group h snapshot (16*512/4)

typedef __bf16 bf16x8 __attribute__((ext_vector_type(8)));
typedef float  f32x4  __attribute__((ext_vector_type(4)));
typedef unsigned short u16;
typedef unsigned int   u32;
typedef unsigned long long u64;
#define SENT (~0ull)

__device__ __forceinline__ u16 f2bf(float x) {
    unsigned int u = __float_as_uint(x);
    u += 0x7FFFu + ((u >> 16) & 1u);
    return (u16)(u >> 16);
}
__device__ __forceinline__ float sigf(float x) { return 1.0f / (1.0f + __expf(-x)); }
__device__ __forceinline__ float tanh_fast(float x) {
    float ax = fabsf(x);
    float e = __expf(-2.0f * ax);
    return copysignf((1.0f - e) / (1.0f + e), x);
}

__global__ void __launch_bounds__(512, 1)
mdn_kernel(const float* __restrict__ inp, const float* __restrict__ Wk,
           const float* __restrict__ Wr,  const float* __restrict__ bg,
           const float* __restrict__ Wd,  const float* __restrict__ bd,
           float* __restrict__ out, u64* __restrict__ hx)
{
    __shared__ __attribute__((aligned(16))) u16  wr_s[64 * HH];   // dead after preamble
    __shared__ __attribute__((aligned(16))) u16  wk_s[64 * 64];   // dead after preamble
    __shared__ __attribute__((aligned(16))) u16  wd_s[16 * HH];   // dead after preamble
    __shared__ __attribute__((aligned(16))) u16  h_s [GB * HH];
    __shared__ __attribute__((aligned(16))) u16  in_s[GB * 64];
    __shared__ __attribute__((aligned(16))) float gbuf[4 * 16 * 16]; // [q][batch][col]
    __shared__ __attribute__((aligned(16))) float pbuf[4 * 16 * 16]; // [kw][batch][col]

    const int tid  = threadIdx.x;
    const int lane = tid & 63;
    const int wave = tid >> 6;
    const int g    = blockIdx.x & 7;    // batch group
    const int s    = blockIdx.x >> 3;   // h-slice 0..31
    const int m16  = lane & 15;
    const int kq   = lane >> 4;

    // ---------------- region A: weight staging + LDS zero-init ----------------
    {
        int n = tid & 63;
        int q = n >> 4, jj = n & 15;
        int col = q * HH + s * 16 + jj;
        for (int k = tid >> 6; k < HH; k += 8)
            wr_s[n * HH + (k ^ ((n & 7) << 3))] = f2bf(Wr[(size_t)k * 2048 + col]);
        for (int k = tid >> 6; k < 64; k += 8)
            wk_s[n * 64 + (k ^ ((n & 7) << 3))] = f2bf(k < DIN ? Wk[(size_t)k * 2048 + col] : 0.0f);
    }
    {
        int n = tid & 15;
        for (int k = tid >> 4; k < HH; k += 32)
            wd_s[n * HH + (k ^ ((n & 7) << 3))] =
                f2bf(n < ODC ? Wd[(size_t)k * OUTC + s * ODC + n] : 0.0f);
    }
    for (int i = tid; i < GB * 64; i += 512) in_s[i] = 0;
    for (int i = tid; i < GB * HH / 8; i += 512) ((uint4*)h_s)[i] = uint4{0,0,0,0}; // h_{-1}=0

    __syncthreads();   // order zero-init before x_0 staging across waves (R3 lesson)

    // ---------------- region B: B-frags to registers, state, x_0 ----------------
    bf16x8 bfr[18];
    if (wave < 4) {
        int n = wave * 16 + m16;
        #pragma unroll
        for (int ks = 0; ks < 16; ++ks) {
            int k0 = 32 * ks + 8 * kq;
            bfr[ks] = *(const bf16x8*)(&wr_s[n * HH + (k0 ^ ((n & 7) << 3))]);
        }
        #pragma unroll
        for (int i = 0; i < 2; ++i) {
            int k0 = 32 * i + 8 * kq;
            bfr[16 + i] = *(const bf16x8*)(&wk_s[n * 64 + (k0 ^ ((n & 7) << 3))]);
        }
    } else {
        int w4 = wave - 4;
        #pragma unroll
        for (int kk = 0; kk < 4; ++kk) {
            int k0 = w4 * 128 + 32 * kk + 8 * kq;
            bfr[kk] = *(const bf16x8*)(&wd_s[m16 * HH + (k0 ^ ((m16 & 7) << 3))]);
        }
    }

    float c_reg = 0.0f;
    float bi = 0.f, bff = 0.f, bgg = 0.f, boo = 0.f, bdv = 0.f;
    int br = 0, jj = 0, oo = 0;
    if (tid < 256) {
        br = tid >> 4; jj = tid & 15;
        int scol = s * 16 + jj;
        bi  = bg[0 * HH + scol];
        bff = bg[1 * HH + scol];
        bgg = bg[2 * HH + scol];
        boo = bg[3 * HH + scol];
        // stage x_0
        const float* ip = inp + ((size_t)(g * GB + br) * TT + 0) * DIN;
        #pragma unroll
        for (int i = 0; i < 3; ++i) {
            int d = jj + 16 * i;
            if (d < DIN) in_s[br * 64 + (d ^ ((br & 7) << 3))] = f2bf(ip[d]);
        }
    } else {
        br = (tid - 256) >> 4; oo = (tid - 256) & 15;
        if (oo < ODC) bdv = bd[s * ODC + oo];
    }
    __syncthreads();

    // poll geometry: thread owns 4 u64 words = 16 h values
    const int pb = tid >> 5;      // batch row 0..15
    const int pk = tid & 31;      // k chunks pk*8 + i*256, i=0,1

    for (int t = 0; t <= TT; ++t) {
        // invariant: h_s = h_{t-1}, in_s = x_t
        // ---- reset own slice words in the buffer that will hold h_{t+1} ----
        // (it holds h_{t-2}: dead, since our step-t poll of h_{t-1} proved every
        //  slice finished reading it. vmcnt(0) below orders reset < h_t stores.)
        if (t < TT && tid < 256 && (jj & 3) == 0) {
            u64* rp = hx + (size_t)((t + 1) % 3) * (NGRP * HWORDS) + g * HWORDS
                         + br * 128 + s * 4 + (jj >> 2);
            __hip_atomic_store(rp, SENT, __ATOMIC_RELAXED, __HIP_MEMORY_SCOPE_AGENT);
        }

        // ---- MFMA phase (B from registers, A from LDS) ----
        if (wave < 4) {
            if (t < TT) {
                f32x4 acc0 = {0.f,0.f,0.f,0.f}, acc1 = {0.f,0.f,0.f,0.f};
                {   // xz contribution (K padded 35->64)
                    int k0 = 8 * kq;
                    bf16x8 a = *(const bf16x8*)(&in_s[m16 * 64 + (k0 ^ ((m16 & 7) << 3))]);
                    acc0 = __builtin_amdgcn_mfma_f32_16x16x32_bf16(a, bfr[16], acc0, 0, 0, 0);
                    int k1 = 32 + 8 * kq;
                    bf16x8 a2 = *(const bf16x8*)(&in_s[m16 * 64 + (k1 ^ ((m16 & 7) << 3))]);
                    acc1 = __builtin_amdgcn_mfma_f32_16x16x32_bf16(a2, bfr[17], acc1, 0, 0, 0);
                }
                #pragma unroll
                for (int ks = 0; ks < 16; ks += 2) {   // h @ Wr, 2-way ILP
                    int k0 = 32 * ks + 8 * kq;
                    bf16x8 a = *(const bf16x8*)(&h_s[m16 * HH + (k0 ^ ((m16 & 7) << 3))]);
                    acc0 = __builtin_amdgcn_mfma_f32_16x16x32_bf16(a, bfr[ks], acc0, 0, 0, 0);
                    int k1 = 32 * (ks + 1) + 8 * kq;
                    bf16x8 a2 = *(const bf16x8*)(&h_s[m16 * HH + (k1 ^ ((m16 & 7) << 3))]);
                    acc1 = __builtin_amdgcn_mfma_f32_16x16x32_bf16(a2, bfr[ks + 1], acc1, 0, 0, 0);
                }
                #pragma unroll
                for (int j = 0; j < 4; ++j)
                    gbuf[wave * 256 + (kq * 4 + j) * 16 + m16] = acc0[j] + acc1[j];
            }
        } else {
            if (t > 0) {    // out row t-1, k-split across waves 4..7
                int w4 = wave - 4;
                f32x4 acc0 = {0.f,0.f,0.f,0.f}, acc1 = {0.f,0.f,0.f,0.f};
                #pragma unroll
                for (int kk = 0; kk < 4; kk += 2) {
                    int k0 = w4 * 128 + 32 * kk + 8 * kq;
                    bf16x8 a = *(const bf16x8*)(&h_s[m16 * HH + (k0 ^ ((m16 & 7) << 3))]);
                    acc0 = __builtin_amdgcn_mfma_f32_16x16x32_bf16(a, bfr[kk], acc0, 0, 0, 0);
                    int k1 = w4 * 128 + 32 * (kk + 1) + 8 * kq;
                    bf16x8 a2 = *(const bf16x8*)(&h_s[m16 * HH + (k1 ^ ((m16 & 7) << 3))]);
                    acc1 = __builtin_amdgcn_mfma_f32_16x16x32_bf16(a2, bfr[kk + 1], acc1, 0, 0, 0);
                }
                #pragma unroll
                for (int j = 0; j < 4; ++j)
                    pbuf[w4 * 256 + (kq * 4 + j) * 16 + m16] = acc0[j] + acc1[j];
            }
        }
        __syncthreads();                                   // #1
        // resets (issued pre-MFMA) must commit before h_t stores below; their
        // acks arrived during the MFMA phase, so this wait is ~free.
        asm volatile("s_waitcnt vmcnt(0)" ::: "memory");

        // ---- scalar phase ----
        if (tid < 256) {
            if (t < TT) {
                float iv = gbuf[0 * 256 + br * 16 + jj] + bi;
                float fv = gbuf[1 * 256 + br * 16 + jj] + bff;
                float gv = gbuf[2 * 256 + br * 16 + jj] + bgg;
                float ov = gbuf[3 * 256 + br * 16 + jj] + boo;
                c_reg = sigf(fv) * c_reg + sigf(iv) * tanh_fast(gv);
                float h = sigf(ov) * tanh_fast(c_reg);
                // pack 4 neighboring cols into one u64 and store (relaxed agent)
                u32 hb = (u32)f2bf(h);
                u32 o1 = (u32)__shfl_xor((int)hb, 1);
                u32 lo = hb | (o1 << 16);                  // valid on even jj
                u32 o2 = (u32)__shfl_xor((int)lo, 2);      // jj%4==0 gets (jj+2,jj+3)
                if ((jj & 3) == 0) {
                    u64 w = (u64)lo | ((u64)o2 << 32);
                    u64* dst = hx + (size_t)(t % 3) * (NGRP * HWORDS) + g * HWORDS
                                  + br * 128 + s * 4 + (jj >> 2);
                    __hip_atomic_store(dst, w, __ATOMIC_RELAXED, __HIP_MEMORY_SCOPE_AGENT);
                }
            }
        } else {
            if (t > 0) {    // reduce out partials + store f32
                float v = pbuf[0 * 256 + br * 16 + oo] + pbuf[1 * 256 + br * 16 + oo]
                        + pbuf[2 * 256 + br * 16 + oo] + pbuf[3 * 256 + br * 16 + oo] + bdv;
                if (oo < ODC)
                    out[((size_t)(g * GB + br) * TT + (t - 1)) * OUTC + s * ODC + oo] = v;
            }
            // prefetch x_{t+1} (only writes d<35 slots; pad stays 0 -> no race)
            if (t + 1 < TT) {
                const float* ip = inp + ((size_t)(g * GB + br) * TT + (t + 1)) * DIN;
                #pragma unroll
                for (int i = 0; i < 3; ++i) {
                    int d = oo + 16 * i;
                    if (d < DIN) in_s[br * 64 + (d ^ ((br & 7) << 3))] = f2bf(ip[d]);
                }
            }
        }

        // ---- poll-on-data: own 4 words of h_t (buf t%3), unpack into h_s ----
        if (t < TT) {
            const u64* bp = hx + (size_t)(t % 3) * (NGRP * HWORDS) + g * HWORDS;
            const int wA = pb * 128 + pk * 2;
            u64 v0 = SENT, v1 = SENT, v2 = SENT, v3 = SENT;
            int spins = 0;
            while (true) {
                if (v0 == SENT) v0 = __hip_atomic_load(bp + wA,      __ATOMIC_RELAXED, __HIP_MEMORY_SCOPE_AGENT);
                if (v1 == SENT) v1 = __hip_atomic_load(bp + wA + 1,  __ATOMIC_RELAXED, __HIP_MEMORY_SCOPE_AGENT);
                if (v2 == SENT) v2 = __hip_atomic_load(bp + wA + 64, __ATOMIC_RELAXED, __HIP_MEMORY_SCOPE_AGENT);
                if (v3 == SENT) v3 = __hip_atomic_load(bp + wA + 65, __ATOMIC_RELAXED, __HIP_MEMORY_SCOPE_AGENT);
                if (v0 != SENT && v1 != SENT && v2 != SENT && v3 != SENT) break;
                if (++spins > (1 << 20)) break;            // bounded bail-out: no hangs
                __builtin_amdgcn_s_sleep(1);
            }
            {
                int k0 = pk * 8, sk0 = k0 ^ ((pb & 7) << 3);
                *(u64*)(&h_s[pb * HH + sk0])     = v0;
                *(u64*)(&h_s[pb * HH + sk0 + 4]) = v1;
                int k1 = pk * 8 + 256, sk1 = k1 ^ ((pb & 7) << 3);
                *(u64*)(&h_s[pb * HH + sk1])     = v2;
                *(u64*)(&h_s[pb * HH + sk1 + 4]) = v3;
            }
            __syncthreads();                               // #2
        }
    }
}

extern "C" void kernel_launch(void* const* d_in, const int* in_sizes, int n_in,
                              void* d_out, int out_size, void* d_ws, size_t ws_size,
                              hipStream_t stream) {
    const float* inp = (const float*)d_in[0];
    const float* Wk  = (const float*)d_in[1];
    const float* Wr  = (const float*)d_in[2];
    const float* bg  = (const float*)d_in[3];
    const float* Wd  = (const float*)d_in[4];
    const float* bd  = (const float*)d_in[5];
    float* out = (float*)d_out;

    // ws: 3 rotating h buffers x 8 groups x 2048 u64 = 384 KB.
    // Memset to 0xFF (sentinel) every launch: bf16 h values are never NaN, so
    // ~0ull words unambiguously mean "not yet written this launch".
    u64* hx = (u64*)d_ws;
    size_t zbytes = (size_t)3 * NGRP * HWORDS * sizeof(u64);
    hipMemsetAsync(d_ws, 0xFF, zbytes, stream);

    hipLaunchKernelGGL(mdn_kernel, dim3(NGRP * NSLICE), dim3(512), 0, stream,
                       inp, Wk, Wr, bg, Wd, bd, out, hx);
}